// Round 1
// baseline (559.691 us; speedup 1.0000x reference)
//
#include <hip/hip_runtime.h>

#define B_ 16
#define N_ 4096
#define C_ 256
#define K_ 8
#define EPS 1e-6f
#define RATIO 0.1f

typedef float f32x4 __attribute__((ext_vector_type(4)));
typedef __bf16 bf16x8 __attribute__((ext_vector_type(8)));

__device__ inline unsigned short f2bf(float f){
  unsigned int u = __float_as_uint(f);
  u += 0x7FFFu + ((u >> 16) & 1u);   // RNE
  return (unsigned short)(u >> 16);
}

// ---------------- K0: init workspace, W1->bf16, W2 transpose, geno logits ----
__global__ __launch_bounds__(256) void k0_prep(
    const float* __restrict__ W1, const float* __restrict__ W2,
    const float* __restrict__ geno, const float* __restrict__ Wgg,
    const float* __restrict__ bgg,
    unsigned short* __restrict__ W1bf, float* __restrict__ W2T,
    float* __restrict__ g, int* __restrict__ cnt,
    float* __restrict__ mass, float* __restrict__ conf,
    float* __restrict__ glog)
{
  int gid = blockIdx.x * 256 + threadIdx.x;           // 65536 threads
  if (gid < B_*K_*C_) g[gid] = 0.f;                   // 32768
  if (gid < B_*K_) { cnt[gid] = 0; mass[gid] = 0.f; }
  if (gid == 0) conf[0] = 0.f;
  for (int i = gid; i < K_*C_*C_; i += 65536) W1bf[i] = f2bf(W1[i]);
  for (int i = gid; i < K_*C_*C_; i += 65536){
    int k = i >> 16, j = (i >> 8) & 255, c = i & 255;
    W2T[i] = W2[(k << 16) + (c << 8) + j];            // W2T[k][j][c] = W2[k][c][j]
  }
  int wv = gid >> 6;                                   // wave id
  if (wv < B_*K_){
    int lane = threadIdx.x & 63;
    int b = wv >> 3, k = wv & 7;
    float4 a = *(const float4*)(geno + b*C_ + lane*4);
    float4 w = *(const float4*)(Wgg  + k*C_ + lane*4);
    float p = a.x*w.x + a.y*w.y + a.z*w.z + a.w*w.w;
    #pragma unroll
    for (int off = 32; off; off >>= 1) p += __shfl_xor(p, off);
    if (lane == 0) glog[wv] = RATIO * (p + bgg[k]);
  }
}

// ---------------- K1: gate (one wave per token), top-2, bucket scatter -------
__global__ __launch_bounds__(256) void k1_gate(
    const float* __restrict__ tokens, const float* __restrict__ Wg,
    const float* __restrict__ bg, const float* __restrict__ glog,
    int* __restrict__ cnt, int* __restrict__ bidx, float* __restrict__ bw,
    float* __restrict__ mass, float* __restrict__ conf)
{
  __shared__ float bg_s[K_], gl_s[K_], mass_s[K_];
  __shared__ float conf_s;
  int tid = threadIdx.x, lane = tid & 63, wave = tid >> 6;
  int b = blockIdx.x >> 6;                 // 64 blocks per batch row
  int tok0 = (blockIdx.x & 63) * 64;
  if (tid < K_){ bg_s[tid] = bg[tid]; gl_s[tid] = glog[b*K_ + tid]; mass_s[tid] = 0.f; }
  if (tid == 0) conf_s = 0.f;
  float4 wreg[K_];                          // each lane holds Wg[k][lane*4..+3]
  #pragma unroll
  for (int k = 0; k < K_; ++k) wreg[k] = *(const float4*)(Wg + k*C_ + lane*4);
  __syncthreads();
  float conf_acc = 0.f;
  for (int i = wave; i < 64; i += 4){
    int n = tok0 + i;
    float4 x = *(const float4*)(tokens + ((size_t)b*N_ + n)*C_ + lane*4);
    float p[K_];
    #pragma unroll
    for (int k = 0; k < K_; ++k){
      float4 w = wreg[k];
      p[k] = x.x*w.x + x.y*w.y + x.z*w.z + x.w*w.w;
    }
    #pragma unroll
    for (int off = 32; off; off >>= 1){
      #pragma unroll
      for (int k = 0; k < K_; ++k) p[k] += __shfl_xor(p[k], off);
    }
    float v0 = -1e30f, v1 = -1e30f; int i0 = 0, i1 = 0;
    #pragma unroll
    for (int k = 0; k < K_; ++k){
      float l = p[k] + bg_s[k] + gl_s[k];
      if (l > v0){ v1 = v0; i1 = i0; v0 = l; i0 = k; }
      else if (l > v1){ v1 = l; i1 = k; }
    }
    if (lane == 0){
      float e  = expf(v1 - v0);
      float w0 = 1.f / (1.f + e), w1 = e / (1.f + e);
      w0 = fmaxf(w0, EPS); w1 = fmaxf(w1, EPS);
      float inv = 1.f / (w0 + w1);
      w0 *= inv; w1 *= inv;
      int p0 = atomicAdd(&cnt[b*K_ + i0], 1);
      bidx[(b*K_ + i0)*N_ + p0] = n;  bw[(b*K_ + i0)*N_ + p0] = w0;
      int p1 = atomicAdd(&cnt[b*K_ + i1], 1);
      bidx[(b*K_ + i1)*N_ + p1] = n;  bw[(b*K_ + i1)*N_ + p1] = w1;
      atomicAdd(&mass_s[i0], w0);
      atomicAdd(&mass_s[i1], w1);
      conf_acc += v0 - v1;
    }
  }
  if (lane == 0) atomicAdd(&conf_s, conf_acc);
  __syncthreads();
  if (tid < K_) atomicAdd(&mass[b*K_ + tid], mass_s[tid]);
  if (tid == 0) atomicAdd(conf, conf_s);
}

// ---------------- K2: lb_loss + routing confidence ---------------------------
__global__ void k2_scalars(const int* __restrict__ cnt, const float* __restrict__ conf,
                           float* __restrict__ out)
{
  __shared__ int kc[K_];
  int tid = threadIdx.x;
  if (tid < K_) kc[tid] = 0;
  __syncthreads();
  if (tid < B_*K_) atomicAdd(&kc[tid & 7], cnt[tid]);
  __syncthreads();
  if (tid == 0){
    float u[K_], mean = 0.f;
    for (int k = 0; k < K_; ++k){ u[k] = (float)kc[k] / (float)(B_*N_); mean += u[k]; }
    mean *= (1.f / K_);
    float var = 0.f;
    for (int k = 0; k < K_; ++k){ float d = u[k] - mean; var += d*d; }
    var *= (1.f / K_);
    float denom = mean + EPS;
    out[B_*K_*C_]     = var / (denom * denom);        // (std/(mean+eps))^2
    out[B_*K_*C_ + 1] = conf[0] / (float)(B_*N_);
  }
}

// ---------------- K4: per-bucket layer-1 MFMA GEMM + weighted reduce ---------
// grid: x = 64-token chunk (0..63), y = bucket (0..127). block = 256.
__global__ __launch_bounds__(256, 2) void k4_expert(
    const float* __restrict__ tokens, const unsigned short* __restrict__ W1bf,
    const float* __restrict__ b1, const int* __restrict__ cnt,
    const int* __restrict__ bidx, const float* __restrict__ bw,
    float* __restrict__ g)
{
  int bucket = blockIdx.y;
  int M = cnt[bucket];
  int chunk = blockIdx.x;
  if (chunk * 64 >= M) return;
  int b = bucket >> 3, k = bucket & 7;

  __shared__ unsigned short Xs[64][264];   // tokens chunk, bf16, +8 pad
  __shared__ unsigned short Ws[64][264];   // W1 j-tile, bf16, +8 pad
  __shared__ float wtok[64];
  __shared__ float b1s[C_];
  __shared__ float gred[4][64];

  int tid = threadIdx.x;
  int r = tid >> 2, q = tid & 3;           // 4 loader threads per row
  if (tid < 64){
    int tn = chunk*64 + tid;
    wtok[tid] = (tn < M) ? bw[bucket*N_ + tn] : 0.f;
  }
  b1s[tid] = b1[k*C_ + tid];
  {
    int tn = chunk*64 + r;
    bool valid = tn < M;
    int n = valid ? bidx[bucket*N_ + tn] : 0;
    const float4* src = (const float4*)(tokens + ((size_t)b*N_ + n)*C_);
    #pragma unroll
    for (int it = 0; it < 16; ++it){
      int c4 = it*4 + q;
      float4 v;
      if (valid) v = src[c4];
      else { v.x = 0.f; v.y = 0.f; v.z = 0.f; v.w = 0.f; }
      ushort4 u; u.x = f2bf(v.x); u.y = f2bf(v.y); u.z = f2bf(v.z); u.w = f2bf(v.w);
      *(ushort4*)&Xs[r][c4*4] = u;
    }
  }
  int lane = tid & 63, wave = tid >> 6, quad = lane >> 4, l16 = lane & 15;
  int q8 = quad * 8;

  for (int jt = 0; jt < 4; ++jt){
    __syncthreads();                        // protect Ws/gred overwrite
    {
      const uint4* wsrc = (const uint4*)(W1bf + (((k*C_) + jt*64 + r) << 8));
      #pragma unroll
      for (int it = 0; it < 8; ++it){
        int cc = it*4 + q;
        *(uint4*)&Ws[r][cc*8] = wsrc[cc];
      }
    }
    __syncthreads();
    f32x4 acc[4];
    #pragma unroll
    for (int t = 0; t < 4; ++t){ acc[t].x=0.f; acc[t].y=0.f; acc[t].z=0.f; acc[t].w=0.f; }
    #pragma unroll
    for (int s = 0; s < 8; ++s){
      // A frag: A[m=l16][kk=quad*8+j] = Xs[wave*16+l16][s*32+quad*8+j]
      bf16x8 a = *(const bf16x8*)&Xs[wave*16 + l16][s*32 + q8];
      #pragma unroll
      for (int t = 0; t < 4; ++t){
        // B frag: B[kk=quad*8+j][n=l16] = W1[j=n][c=kk]
        bf16x8 bb = *(const bf16x8*)&Ws[t*16 + l16][s*32 + q8];
        acc[t] = __builtin_amdgcn_mfma_f32_16x16x32_bf16(a, bb, acc[t], 0, 0, 0);
      }
    }
    // epilogue: relu + bias, weight by token, reduce over tokens
    #pragma unroll
    for (int t = 0; t < 4; ++t){
      float pt = 0.f;
      #pragma unroll
      for (int rr = 0; rr < 4; ++rr){
        int tokr = wave*16 + quad*4 + rr;   // D row = quad*4+reg
        float h = acc[t][rr] + b1s[jt*64 + t*16 + l16];
        h = fmaxf(h, 0.f);
        pt += wtok[tokr] * h;
      }
      pt += __shfl_down(pt, 32);
      pt += __shfl_down(pt, 16);
      if (lane < 16) gred[wave][t*16 + lane] = pt;
    }
    __syncthreads();
    if (tid < 64){
      float s = gred[0][tid] + gred[1][tid] + gred[2][tid] + gred[3][tid];
      atomicAdd(&g[bucket*C_ + jt*64 + tid], s);
    }
  }
}

// ---------------- K5: layer-2 on reduced hidden + divide by mass -------------
__global__ __launch_bounds__(256) void k5_centers(
    const float* __restrict__ g, const float* __restrict__ W2T,
    const float* __restrict__ b2, const float* __restrict__ mass,
    float* __restrict__ out)
{
  __shared__ float gv[C_];
  int z = blockIdx.x, tid = threadIdx.x;
  int k = z & 7;
  gv[tid] = g[z*C_ + tid];
  __syncthreads();
  float m = mass[z];
  float inv = 1.f / fmaxf(m, EPS);
  const float* wp = W2T + (k << 16);
  float dot = 0.f;
  #pragma unroll 4
  for (int j = 0; j < C_; ++j) dot += gv[j] * wp[(j << 8) + tid];
  out[z*C_ + tid] = (dot + m * b2[k*C_ + tid]) * inv;
}

extern "C" void kernel_launch(void* const* d_in, const int* in_sizes, int n_in,
                              void* d_out, int out_size, void* d_ws, size_t ws_size,
                              hipStream_t stream)
{
  const float* tokens = (const float*)d_in[0];
  const float* geno   = (const float*)d_in[1];
  const float* Wg     = (const float*)d_in[2];
  const float* bg     = (const float*)d_in[3];
  const float* Wgg    = (const float*)d_in[4];
  const float* bgg    = (const float*)d_in[5];
  const float* W1     = (const float*)d_in[6];
  const float* b1     = (const float*)d_in[7];
  const float* W2     = (const float*)d_in[8];
  const float* b2     = (const float*)d_in[9];
  float* out = (float*)d_out;
  char* ws = (char*)d_ws;
  // ws layout (bytes): total ~7.2 MB
  unsigned short* W1bf = (unsigned short*)(ws);            // 1,048,576
  float* W2T  = (float*)(ws + 1048576);                    // 2,097,152
  float* g    = (float*)(ws + 3145728);                    //   131,072
  float* glog = (float*)(ws + 3276800);                    //       512
  int*   cnt  = (int*)  (ws + 3277312);                    //       512
  float* mass = (float*)(ws + 3277824);                    //       512
  float* conf = (float*)(ws + 3278336);                    //        64
  int*   bidx = (int*)  (ws + 3278400);                    // 2,097,152
  float* bw   = (float*)(ws + 5375552);                    // 2,097,152

  k0_prep<<<256, 256, 0, stream>>>(W1, W2, geno, Wgg, bgg, W1bf, W2T, g, cnt, mass, conf, glog);
  k1_gate<<<1024, 256, 0, stream>>>(tokens, Wg, bg, glog, cnt, bidx, bw, mass, conf);
  k2_scalars<<<1, 128, 0, stream>>>(cnt, conf, out);
  k4_expert<<<dim3(64, 128), 256, 0, stream>>>(tokens, W1bf, b1, cnt, bidx, bw, g);
  k5_centers<<<128, 256, 0, stream>>>(g, W2T, b2, mass, out);
}

// Round 2
// 291.438 us; speedup vs baseline: 1.9204x; 1.9204x over previous
//
#include <hip/hip_runtime.h>

#define B_ 16
#define N_ 4096
#define C_ 256
#define K_ 8
#define EPS 1e-6f
#define RATIO 0.1f

typedef float f32x4 __attribute__((ext_vector_type(4)));
typedef __bf16 bf16x8 __attribute__((ext_vector_type(8)));

__device__ inline unsigned short f2bf(float f){
  unsigned int u = __float_as_uint(f);
  u += 0x7FFFu + ((u >> 16) & 1u);   // RNE
  return (unsigned short)(u >> 16);
}

// ---------------- K0: init workspace, W1->bf16, W2 transpose, geno logits ----
__global__ __launch_bounds__(256) void k0_prep(
    const float* __restrict__ W1, const float* __restrict__ W2,
    const float* __restrict__ geno, const float* __restrict__ Wgg,
    const float* __restrict__ bgg,
    unsigned short* __restrict__ W1bf, float* __restrict__ W2T,
    float* __restrict__ g, int* __restrict__ cnt,
    float* __restrict__ mass, float* __restrict__ conf,
    float* __restrict__ glog)
{
  int gid = blockIdx.x * 256 + threadIdx.x;           // 65536 threads
  if (gid < B_*K_*C_) g[gid] = 0.f;                   // 32768
  if (gid < B_*K_) { cnt[gid] = 0; mass[gid] = 0.f; }
  if (gid == 0) conf[0] = 0.f;
  for (int i = gid; i < K_*C_*C_; i += 65536) W1bf[i] = f2bf(W1[i]);
  for (int i = gid; i < K_*C_*C_; i += 65536){
    int k = i >> 16, j = (i >> 8) & 255, c = i & 255;
    W2T[i] = W2[(k << 16) + (c << 8) + j];            // W2T[k][j][c] = W2[k][c][j]
  }
  int wv = gid >> 6;                                   // wave id
  if (wv < B_*K_){
    int lane = threadIdx.x & 63;
    int b = wv >> 3, k = wv & 7;
    float4 a = *(const float4*)(geno + b*C_ + lane*4);
    float4 w = *(const float4*)(Wgg  + k*C_ + lane*4);
    float p = a.x*w.x + a.y*w.y + a.z*w.z + a.w*w.w;
    #pragma unroll
    for (int off = 32; off; off >>= 1) p += __shfl_xor(p, off);
    if (lane == 0) glog[wv] = RATIO * (p + bgg[k]);
  }
}

// ---------------- K1: gate (one wave per token), top-2, LDS-local bucketing --
// Global atomics: 8 per block (one per expert) instead of 2 per token.
__global__ __launch_bounds__(256) void k1_gate(
    const float* __restrict__ tokens, const float* __restrict__ Wg,
    const float* __restrict__ bg, const float* __restrict__ glog,
    int* __restrict__ cnt, int* __restrict__ bidx, float* __restrict__ bw,
    float* __restrict__ mass, float* __restrict__ conf)
{
  __shared__ float bg_s[K_], gl_s[K_], mass_s[K_];
  __shared__ int lcnt[K_], gbase[K_];
  __shared__ float conf_s;
  __shared__ int   e0s[64], e1s[64], s0s[64], s1s[64];
  __shared__ float w0s[64], w1s[64];
  int tid = threadIdx.x, lane = tid & 63, wave = tid >> 6;
  int b = blockIdx.x >> 6;                 // 64 blocks per batch row
  int tok0 = (blockIdx.x & 63) * 64;
  if (tid < K_){ bg_s[tid] = bg[tid]; gl_s[tid] = glog[b*K_ + tid];
                 mass_s[tid] = 0.f; lcnt[tid] = 0; }
  if (tid == 0) conf_s = 0.f;
  float4 wreg[K_];                          // each lane holds Wg[k][lane*4..+3]
  #pragma unroll
  for (int k = 0; k < K_; ++k) wreg[k] = *(const float4*)(Wg + k*C_ + lane*4);
  __syncthreads();
  float conf_acc = 0.f;
  for (int i = wave; i < 64; i += 4){
    int n = tok0 + i;
    float4 x = *(const float4*)(tokens + ((size_t)b*N_ + n)*C_ + lane*4);
    float p[K_];
    #pragma unroll
    for (int k = 0; k < K_; ++k){
      float4 w = wreg[k];
      p[k] = x.x*w.x + x.y*w.y + x.z*w.z + x.w*w.w;
    }
    #pragma unroll
    for (int off = 32; off; off >>= 1){
      #pragma unroll
      for (int k = 0; k < K_; ++k) p[k] += __shfl_xor(p[k], off);
    }
    float v0 = -1e30f, v1 = -1e30f; int i0 = 0, i1 = 0;
    #pragma unroll
    for (int k = 0; k < K_; ++k){
      float l = p[k] + bg_s[k] + gl_s[k];
      if (l > v0){ v1 = v0; i1 = i0; v0 = l; i0 = k; }
      else if (l > v1){ v1 = l; i1 = k; }
    }
    if (lane == 0){
      float e  = expf(v1 - v0);
      float w0 = 1.f / (1.f + e), w1 = e / (1.f + e);
      w0 = fmaxf(w0, EPS); w1 = fmaxf(w1, EPS);
      float inv = 1.f / (w0 + w1);
      w0 *= inv; w1 *= inv;
      int p0 = atomicAdd(&lcnt[i0], 1);     // LDS-local slot reservation
      int p1 = atomicAdd(&lcnt[i1], 1);
      e0s[i] = i0; e1s[i] = i1; s0s[i] = p0; s1s[i] = p1;
      w0s[i] = w0; w1s[i] = w1;
      atomicAdd(&mass_s[i0], w0);
      atomicAdd(&mass_s[i1], w1);
      conf_acc += v0 - v1;
    }
  }
  if (lane == 0) atomicAdd(&conf_s, conf_acc);
  __syncthreads();
  if (tid < K_){                            // ONE global RMW per expert per block
    gbase[tid] = atomicAdd(&cnt[b*K_ + tid], lcnt[tid]);
    atomicAdd(&mass[b*K_ + tid], mass_s[tid]);
  }
  if (tid == 0) atomicAdd(conf, conf_s);
  __syncthreads();
  if (tid < 64){                            // compacted scatter, fully parallel
    int n = tok0 + tid;
    int ke0 = e0s[tid], ke1 = e1s[tid];
    size_t o0 = (size_t)(b*K_ + ke0)*N_ + gbase[ke0] + s0s[tid];
    size_t o1 = (size_t)(b*K_ + ke1)*N_ + gbase[ke1] + s1s[tid];
    bidx[o0] = n;  bw[o0] = w0s[tid];
    bidx[o1] = n;  bw[o1] = w1s[tid];
  }
}

// ---------------- K2: lb_loss + routing confidence ---------------------------
__global__ void k2_scalars(const int* __restrict__ cnt, const float* __restrict__ conf,
                           float* __restrict__ out)
{
  __shared__ int kc[K_];
  int tid = threadIdx.x;
  if (tid < K_) kc[tid] = 0;
  __syncthreads();
  if (tid < B_*K_) atomicAdd(&kc[tid & 7], cnt[tid]);
  __syncthreads();
  if (tid == 0){
    float u[K_], mean = 0.f;
    for (int k = 0; k < K_; ++k){ u[k] = (float)kc[k] / (float)(B_*N_); mean += u[k]; }
    mean *= (1.f / K_);
    float var = 0.f;
    for (int k = 0; k < K_; ++k){ float d = u[k] - mean; var += d*d; }
    var *= (1.f / K_);
    float denom = mean + EPS;
    out[B_*K_*C_]     = var / (denom * denom);        // (std/(mean+eps))^2
    out[B_*K_*C_ + 1] = conf[0] / (float)(B_*N_);
  }
}

// ---------------- K4: per-bucket layer-1 MFMA GEMM + weighted reduce ---------
// grid: x = 64-token chunk (0..63), y = bucket (0..127). block = 256.
__global__ __launch_bounds__(256, 2) void k4_expert(
    const float* __restrict__ tokens, const unsigned short* __restrict__ W1bf,
    const float* __restrict__ b1, const int* __restrict__ cnt,
    const int* __restrict__ bidx, const float* __restrict__ bw,
    float* __restrict__ g)
{
  int bucket = blockIdx.y;
  int M = cnt[bucket];
  int chunk = blockIdx.x;
  if (chunk * 64 >= M) return;
  int b = bucket >> 3, k = bucket & 7;

  __shared__ unsigned short Xs[64][264];   // tokens chunk, bf16, +8 pad
  __shared__ unsigned short Ws[64][264];   // W1 j-tile, bf16, +8 pad
  __shared__ float wtok[64];
  __shared__ float b1s[C_];
  __shared__ float gred[4][64];

  int tid = threadIdx.x;
  int r = tid >> 2, q = tid & 3;           // 4 loader threads per row
  if (tid < 64){
    int tn = chunk*64 + tid;
    wtok[tid] = (tn < M) ? bw[bucket*N_ + tn] : 0.f;
  }
  b1s[tid] = b1[k*C_ + tid];
  {
    int tn = chunk*64 + r;
    bool valid = tn < M;
    int n = valid ? bidx[bucket*N_ + tn] : 0;
    const float4* src = (const float4*)(tokens + ((size_t)b*N_ + n)*C_);
    #pragma unroll
    for (int it = 0; it < 16; ++it){
      int c4 = it*4 + q;
      float4 v;
      if (valid) v = src[c4];
      else { v.x = 0.f; v.y = 0.f; v.z = 0.f; v.w = 0.f; }
      ushort4 u; u.x = f2bf(v.x); u.y = f2bf(v.y); u.z = f2bf(v.z); u.w = f2bf(v.w);
      *(ushort4*)&Xs[r][c4*4] = u;
    }
  }
  int lane = tid & 63, wave = tid >> 6, quad = lane >> 4, l16 = lane & 15;
  int q8 = quad * 8;

  for (int jt = 0; jt < 4; ++jt){
    __syncthreads();                        // protect Ws/gred overwrite
    {
      const uint4* wsrc = (const uint4*)(W1bf + (((k*C_) + jt*64 + r) << 8));
      #pragma unroll
      for (int it = 0; it < 8; ++it){
        int cc = it*4 + q;
        *(uint4*)&Ws[r][cc*8] = wsrc[cc];
      }
    }
    __syncthreads();
    f32x4 acc[4];
    #pragma unroll
    for (int t = 0; t < 4; ++t){ acc[t].x=0.f; acc[t].y=0.f; acc[t].z=0.f; acc[t].w=0.f; }
    #pragma unroll
    for (int s = 0; s < 8; ++s){
      // A frag: A[m=l16][kk=quad*8+j] = Xs[wave*16+l16][s*32+quad*8+j]
      bf16x8 a = *(const bf16x8*)&Xs[wave*16 + l16][s*32 + q8];
      #pragma unroll
      for (int t = 0; t < 4; ++t){
        // B frag: B[kk=quad*8+j][n=l16] = W1[j=n][c=kk]
        bf16x8 bb = *(const bf16x8*)&Ws[t*16 + l16][s*32 + q8];
        acc[t] = __builtin_amdgcn_mfma_f32_16x16x32_bf16(a, bb, acc[t], 0, 0, 0);
      }
    }
    // epilogue: relu + bias, weight by token, reduce over tokens
    #pragma unroll
    for (int t = 0; t < 4; ++t){
      float pt = 0.f;
      #pragma unroll
      for (int rr = 0; rr < 4; ++rr){
        int tokr = wave*16 + quad*4 + rr;   // D row = quad*4+reg
        float h = acc[t][rr] + b1s[jt*64 + t*16 + l16];
        h = fmaxf(h, 0.f);
        pt += wtok[tokr] * h;
      }
      pt += __shfl_down(pt, 32);
      pt += __shfl_down(pt, 16);
      if (lane < 16) gred[wave][t*16 + lane] = pt;
    }
    __syncthreads();
    if (tid < 64){
      float s = gred[0][tid] + gred[1][tid] + gred[2][tid] + gred[3][tid];
      atomicAdd(&g[bucket*C_ + jt*64 + tid], s);
    }
  }
}

// ---------------- K5: layer-2 on reduced hidden + divide by mass -------------
__global__ __launch_bounds__(256) void k5_centers(
    const float* __restrict__ g, const float* __restrict__ W2T,
    const float* __restrict__ b2, const float* __restrict__ mass,
    float* __restrict__ out)
{
  __shared__ float gv[C_];
  int z = blockIdx.x, tid = threadIdx.x;
  int k = z & 7;
  gv[tid] = g[z*C_ + tid];
  __syncthreads();
  float m = mass[z];
  float inv = 1.f / fmaxf(m, EPS);
  const float* wp = W2T + (k << 16);
  float dot = 0.f;
  #pragma unroll 4
  for (int j = 0; j < C_; ++j) dot += gv[j] * wp[(j << 8) + tid];
  out[z*C_ + tid] = (dot + m * b2[k*C_ + tid]) * inv;
}

extern "C" void kernel_launch(void* const* d_in, const int* in_sizes, int n_in,
                              void* d_out, int out_size, void* d_ws, size_t ws_size,
                              hipStream_t stream)
{
  const float* tokens = (const float*)d_in[0];
  const float* geno   = (const float*)d_in[1];
  const float* Wg     = (const float*)d_in[2];
  const float* bg     = (const float*)d_in[3];
  const float* Wgg    = (const float*)d_in[4];
  const float* bgg    = (const float*)d_in[5];
  const float* W1     = (const float*)d_in[6];
  const float* b1     = (const float*)d_in[7];
  const float* W2     = (const float*)d_in[8];
  const float* b2     = (const float*)d_in[9];
  float* out = (float*)d_out;
  char* ws = (char*)d_ws;
  // ws layout (bytes): total ~7.2 MB
  unsigned short* W1bf = (unsigned short*)(ws);            // 1,048,576
  float* W2T  = (float*)(ws + 1048576);                    // 2,097,152
  float* g    = (float*)(ws + 3145728);                    //   131,072
  float* glog = (float*)(ws + 3276800);                    //       512
  int*   cnt  = (int*)  (ws + 3277312);                    //       512
  float* mass = (float*)(ws + 3277824);                    //       512
  float* conf = (float*)(ws + 3278336);                    //        64
  int*   bidx = (int*)  (ws + 3278400);                    // 2,097,152
  float* bw   = (float*)(ws + 5375552);                    // 2,097,152

  k0_prep<<<256, 256, 0, stream>>>(W1, W2, geno, Wgg, bgg, W1bf, W2T, g, cnt, mass, conf, glog);
  k1_gate<<<1024, 256, 0, stream>>>(tokens, Wg, bg, glog, cnt, bidx, bw, mass, conf);
  k2_scalars<<<1, 128, 0, stream>>>(cnt, conf, out);
  k4_expert<<<dim3(64, 128), 256, 0, stream>>>(tokens, W1bf, b1, cnt, bidx, bw, g);
  k5_centers<<<128, 256, 0, stream>>>(g, W2T, b2, mass, out);
}